// Round 3
// baseline (50.145 us; speedup 1.0000x reference)
//
#include <hip/hip_runtime.h>

// DynamicFiltering: out[b,c,y,x] = sum_{ki,kj} padded_img[b,c,y+ki,x+kj] * kernels[b,c,ki*3+kj,y,x]
// img: [B,C,H,W] f32; kernels: [B,C,9,H,W] f32; out: [B,C,H,W] f32. pad=1 (zeros).
// Memory-bound: kernels tensor (226.5 MB, zero reuse) dominates.
// R2->R3: fix nontemporal builtins by using clang ext_vector_type instead of
// HIP float4 (the builtin requires a native vector type).

constexpr int B = 8, C = 3, H = 512, W = 512;
constexpr int W4 = W / 4;

typedef float floatx4 __attribute__((ext_vector_type(4)));

__global__ __launch_bounds__(256) void dynfilt_kernel(
    const float* __restrict__ img,
    const float* __restrict__ kern,
    float* __restrict__ out)
{
    const int tid = blockIdx.x * blockDim.x + threadIdx.x;

    const int x4 = tid & (W4 - 1);
    const int y  = (tid >> 7) & (H - 1);     // tid / W4 % H  (W4 = 128 = 2^7)
    const int bc = tid >> 16;                // tid / (W4*H)  (W4*H = 65536 = 2^16)
    const int x0 = x4 << 2;

    constexpr size_t plane = (size_t)H * W;
    const float* imgp  = img  + (size_t)bc * plane;
    const float* kernp = kern + (size_t)bc * 9 * plane + (size_t)y * W + x0;

    // Load 3x6 image window (rows y-1..y+1, cols x0-1..x0+4), zero-padded.
    float win[3][6];
    #pragma unroll
    for (int ki = 0; ki < 3; ++ki) {
        const int yy = y + ki - 1;
        if (yy < 0 || yy >= H) {
            #pragma unroll
            for (int j = 0; j < 6; ++j) win[ki][j] = 0.0f;
        } else {
            const float* rowp = imgp + (size_t)yy * W + x0;
            const floatx4 v = *reinterpret_cast<const floatx4*>(rowp);
            win[ki][1] = v.x; win[ki][2] = v.y; win[ki][3] = v.z; win[ki][4] = v.w;
            win[ki][0] = (x0 > 0)      ? rowp[-1] : 0.0f;
            win[ki][5] = (x0 + 4 < W)  ? rowp[4]  : 0.0f;
        }
    }

    floatx4 acc = (floatx4)(0.0f);
    #pragma unroll
    for (int ki = 0; ki < 3; ++ki) {
        #pragma unroll
        for (int kj = 0; kj < 3; ++kj) {
            const int kk = ki * 3 + kj;
            const floatx4 kv = __builtin_nontemporal_load(
                reinterpret_cast<const floatx4*>(kernp + (size_t)kk * plane));
            acc.x = fmaf(win[ki][0 + kj], kv.x, acc.x);
            acc.y = fmaf(win[ki][1 + kj], kv.y, acc.y);
            acc.z = fmaf(win[ki][2 + kj], kv.z, acc.z);
            acc.w = fmaf(win[ki][3 + kj], kv.w, acc.w);
        }
    }

    __builtin_nontemporal_store(acc,
        reinterpret_cast<floatx4*>(out + (size_t)bc * plane + (size_t)y * W + x0));
}

extern "C" void kernel_launch(void* const* d_in, const int* in_sizes, int n_in,
                              void* d_out, int out_size, void* d_ws, size_t ws_size,
                              hipStream_t stream)
{
    const float* img  = (const float*)d_in[0];
    const float* kern = (const float*)d_in[1];
    float* out = (float*)d_out;

    const int total = B * C * H * W4;          // 1,572,864 threads, no tail
    const int block = 256;
    const int grid = total / block;            // 6144 blocks
    dynfilt_kernel<<<grid, block, 0, stream>>>(img, kern, out);
}

// Round 4
// 46.400 us; speedup vs baseline: 1.0807x; 1.0807x over previous
//
#include <hip/hip_runtime.h>

// DynamicFiltering: out[b,c,y,x] = sum_{ki,kj} padded_img[b,c,y+ki,x+kj] * kernels[b,c,ki*3+kj,y,x]
// img: [B,C,H,W] f32; kernels: [B,C,9,H,W] f32; out: [B,C,H,W] f32. pad=1 (zeros).
// Memory-bound: kernels tensor (226.5 MB, zero reuse) dominates; mandatory
// traffic = 277 MB. R3->R4: (a) 2 output rows per thread (4-row img window
// serves 2 outputs -> img overfetch 2x -> 1.5x, 2x in-flight loads),
// (b) chunked XCD swizzle so halo-sharing blocks land on the same XCD L2,
// (c) drop nontemporal (R3 showed neutral/negative).

constexpr int B = 8, C = 3, H = 512, W = 512;
constexpr int W4 = W / 4;        // 128 float4 per row
constexpr int H2 = H / 2;        // 256 row-pairs
constexpr int NBLK = B * C * H2 * W4 / 256;   // 3072 blocks
constexpr int NXCD = 8;
constexpr int BLK_PER_XCD = NBLK / NXCD;      // 384

typedef float floatx4 __attribute__((ext_vector_type(4)));

__global__ __launch_bounds__(256) void dynfilt_kernel(
    const float* __restrict__ img,
    const float* __restrict__ kern,
    float* __restrict__ out)
{
    // Chunked XCD swizzle: hw blocks round-robin across XCDs; remap so each
    // XCD owns a contiguous chunk of logical blocks (halo rows share L2).
    const int bid  = blockIdx.x;
    const int lbid = (bid & (NXCD - 1)) * BLK_PER_XCD + (bid >> 3);
    const int tid  = lbid * 256 + threadIdx.x;

    const int x4 = tid & (W4 - 1);           // 7 bits
    const int yh = (tid >> 7) & (H2 - 1);    // 8 bits
    const int bc = tid >> 15;                // / (W4*H2)
    const int x0 = x4 << 2;
    const int y0 = yh << 1;                  // even output row; also does y0+1

    constexpr size_t plane = (size_t)H * W;
    const float* imgp = img + (size_t)bc * plane;

    // Image window: rows y0-1 .. y0+2 (4 rows), cols x0-1 .. x0+4 (6 cols).
    float win[4][6];
    #pragma unroll
    for (int r = 0; r < 4; ++r) {
        const int yy = y0 - 1 + r;
        if (yy < 0 || yy >= H) {             // only r==0 (y0==0) or r==3 (y0==H-2)
            #pragma unroll
            for (int j = 0; j < 6; ++j) win[r][j] = 0.0f;
        } else {
            const float* rowp = imgp + (size_t)yy * W + x0;
            const floatx4 v = *reinterpret_cast<const floatx4*>(rowp);
            win[r][1] = v.x; win[r][2] = v.y; win[r][3] = v.z; win[r][4] = v.w;
            win[r][0] = (x0 > 0)     ? rowp[-1] : 0.0f;
            win[r][5] = (x0 + 4 < W) ? rowp[4]  : 0.0f;
        }
    }

    const float* kernp0 = kern + (size_t)bc * 9 * plane + (size_t)y0 * W + x0;
    const float* kernp1 = kernp0 + W;

    floatx4 acc0 = (floatx4)(0.0f);
    floatx4 acc1 = (floatx4)(0.0f);
    #pragma unroll
    for (int ki = 0; ki < 3; ++ki) {
        #pragma unroll
        for (int kj = 0; kj < 3; ++kj) {
            const size_t koff = (size_t)(ki * 3 + kj) * plane;
            const floatx4 kv0 = *reinterpret_cast<const floatx4*>(kernp0 + koff);
            const floatx4 kv1 = *reinterpret_cast<const floatx4*>(kernp1 + koff);
            // output row y0 uses window rows ki; row y0+1 uses ki+1
            acc0.x = fmaf(win[ki    ][0 + kj], kv0.x, acc0.x);
            acc0.y = fmaf(win[ki    ][1 + kj], kv0.y, acc0.y);
            acc0.z = fmaf(win[ki    ][2 + kj], kv0.z, acc0.z);
            acc0.w = fmaf(win[ki    ][3 + kj], kv0.w, acc0.w);
            acc1.x = fmaf(win[ki + 1][0 + kj], kv1.x, acc1.x);
            acc1.y = fmaf(win[ki + 1][1 + kj], kv1.y, acc1.y);
            acc1.z = fmaf(win[ki + 1][2 + kj], kv1.z, acc1.z);
            acc1.w = fmaf(win[ki + 1][3 + kj], kv1.w, acc1.w);
        }
    }

    float* outp = out + (size_t)bc * plane + (size_t)y0 * W + x0;
    *reinterpret_cast<floatx4*>(outp)     = acc0;
    *reinterpret_cast<floatx4*>(outp + W) = acc1;
}

extern "C" void kernel_launch(void* const* d_in, const int* in_sizes, int n_in,
                              void* d_out, int out_size, void* d_ws, size_t ws_size,
                              hipStream_t stream)
{
    const float* img  = (const float*)d_in[0];
    const float* kern = (const float*)d_in[1];
    float* out = (float*)d_out;

    dynfilt_kernel<<<NBLK, 256, 0, stream>>>(img, kern, out);
}